// Round 12
// baseline (288.068 us; speedup 1.0000x reference)
//
#include <hip/hip_runtime.h>

typedef unsigned long long ull;

#define HH 256
#define WW 256
#define PLANE (HH*WW)
#define TILE_R 32
#define TILE_C 64
#define TT 8
#define ER 48                // ext rows
#define EC 80                // ext cols -> 40 pairs
#define NCP 40
#define NTHR 256             // 4 waves; wave w owns ext rows [12w, 12w+12)
#define BAND 12
#define RS 160               // floats per LDS row (40 pairs x 4)
#define LBUF (4 + ER*RS + 4) // 7688 floats per buffer
#define CPP 12               // coeff floats per pair (10 used + 2 pad, 48B = 16B-aligned)
#define SMEM_FLOATS (2*LBUF + ER*NCP*CPP)   // 15376 + 23040 = 38416 (153,664 B)

#define RING_OFS (2u*1024u*1024u)   // float offset of ring slot 1 (8 MB)
#define FLAG_OFS (4u*1024u*1024u)   // float offset of flag array (16 MB)
#define RIMG (HH*(WW/2)*4)
#define NBLK 256

// one DOUBLE Jacobi step (iters s, s+1) for wave band [rb0, rb0+12):
// A (iter s) computed in registers for rows rb0-1..rb0+12, own pair;
// horizontal A-neighbors via ds_bpermute (wave-synchronous);
// B (iter s+1) written to wb for rows rb0..rb0+11. One barrier per call (outside).
__device__ __forceinline__ void hs_interval2(
    const float* __restrict__ rbuf, float* __restrict__ wbuf,
    const float* __restrict__ coef,
    int fb, int cpc, int rb0, int idxL, int idxR, bool wr)
{
    float4 ph[3], pc[3], Ah[3], Ac[2], cf0[2], cf1[2];
    float2 cf2[2];
    #pragma unroll
    for (int i = 0; i < 16; ++i) {
        int r  = rb0 - 2 + i;
        int rc = r < 0 ? 0 : (r > ER-1 ? ER-1 : r);
        // read prev-iter row rc (own pair + edges; unclamped L/R hit pads -> ring-0 only)
        const float* pr = rbuf + RS*rc + fb;
        float2 L = *(const float2*)(pr - 2);
        float4 M = *(const float4*)(pr);
        float2 R = *(const float2*)(pr + 4);
        float4 h;
        h.x = fmaf(2.f, M.x, L.x) + M.z;  h.y = fmaf(2.f, M.z, M.x) + R.x;
        h.z = fmaf(2.f, M.y, L.y) + M.w;  h.w = fmaf(2.f, M.w, M.y) + R.y;
        ph[0] = ph[1]; ph[1] = ph[2]; ph[2] = h;
        pc[0] = pc[1]; pc[1] = pc[2]; pc[2] = M;

        if (i >= 2) {
            int ra  = r - 1;
            int rac = ra < 0 ? 0 : (ra > ER-1 ? ER-1 : ra);
            const float* cp_ = coef + (rac*NCP + cpc)*CPP;
            float4 k0 = *(const float4*)(cp_);      // ca.x ca.y cb.x cb.y
            float4 k1 = *(const float4*)(cp_ + 4);  // cc.x cc.y cd.x cd.y
            float2 k2 = *(const float2*)(cp_ + 8);  // ce.x ce.y
            // A: iter-s update at row ra (own 2 cols)
            float tux = fmaf(-4.f, pc[1].x, fmaf(2.f, ph[1].x, ph[0].x) + ph[2].x);
            float tuy = fmaf(-4.f, pc[1].z, fmaf(2.f, ph[1].y, ph[0].y) + ph[2].y);
            float tvx = fmaf(-4.f, pc[1].y, fmaf(2.f, ph[1].z, ph[0].z) + ph[2].z);
            float tvy = fmaf(-4.f, pc[1].w, fmaf(2.f, ph[1].w, ph[0].w) + ph[2].w);
            float4 av;
            av.x = fmaf(k0.x, tux, -fmaf(k0.z, tvx, k1.x));   // u col0
            av.y = fmaf(k1.z, tvx, -fmaf(k0.z, tux, k2.x));   // v col0
            av.z = fmaf(k0.y, tuy, -fmaf(k0.w, tvy, k1.y));   // u col1
            av.w = fmaf(k1.w, tvy, -fmaf(k0.w, tuy, k2.y));   // v col1
            // horizontal neighbors of A from adjacent lanes (wave-synchronous)
            float uL = __int_as_float(__builtin_amdgcn_ds_bpermute(idxL, __float_as_int(av.z)));
            float vL = __int_as_float(__builtin_amdgcn_ds_bpermute(idxL, __float_as_int(av.w)));
            float uR = __int_as_float(__builtin_amdgcn_ds_bpermute(idxR, __float_as_int(av.x)));
            float vR = __int_as_float(__builtin_amdgcn_ds_bpermute(idxR, __float_as_int(av.y)));
            float4 ah;
            ah.x = fmaf(2.f, av.x, uL) + av.z;  ah.y = fmaf(2.f, av.z, av.x) + uR;
            ah.z = fmaf(2.f, av.y, vL) + av.w;  ah.w = fmaf(2.f, av.w, av.y) + vR;
            Ah[0] = Ah[1]; Ah[1] = Ah[2]; Ah[2] = ah;
            Ac[0] = Ac[1]; Ac[1] = av;
            cf0[0] = cf0[1]; cf0[1] = k0;
            cf1[0] = cf1[1]; cf1[1] = k1;
            cf2[0] = cf2[1]; cf2[1] = k2;

            if (i >= 4) {
                int rb2 = r - 2;                       // in [rb0, rb0+11]
                float4 K0 = cf0[0], K1 = cf1[0]; float2 K2 = cf2[0];
                float Tux = fmaf(-4.f, Ac[0].x, fmaf(2.f, Ah[1].x, Ah[0].x) + Ah[2].x);
                float Tuy = fmaf(-4.f, Ac[0].z, fmaf(2.f, Ah[1].y, Ah[0].y) + Ah[2].y);
                float Tvx = fmaf(-4.f, Ac[0].y, fmaf(2.f, Ah[1].z, Ah[0].z) + Ah[2].z);
                float Tvy = fmaf(-4.f, Ac[0].w, fmaf(2.f, Ah[1].w, Ah[0].w) + Ah[2].w);
                float4 bv;
                bv.x = fmaf(K0.x, Tux, -fmaf(K0.z, Tvx, K1.x));
                bv.y = fmaf(K1.z, Tvx, -fmaf(K0.z, Tux, K2.x));
                bv.z = fmaf(K0.y, Tuy, -fmaf(K0.w, Tvy, K1.y));
                bv.w = fmaf(K1.w, Tvy, -fmaf(K0.w, Tuy, K2.y));
                if (wr) *(float4*)(wbuf + RS*rb2 + fb) = bv;
            }
        }
    }
}

__global__ __launch_bounds__(NTHR, 1)
void hs_mega(const float* __restrict__ x,     // (8,3,256,256): It, Ix, Iy
             const float* __restrict__ est,   // (8,2,256,256): u0, v0
             float* __restrict__ out,         // (8,2,256,256)
             float* __restrict__ ws)          // rings (double-buffered) + flags
{
    extern __shared__ __align__(16) float smem[];
    float* s0   = smem;
    float* s1   = smem + LBUF;
    float* coef = smem + 2*LBUF;

    const int img = blockIdx.x, cs = blockIdx.y, rb = blockIdx.z;
    const int tid = threadIdx.x;
    const int er0 = rb*TILE_R - TT;
    const int ec0 = cs*TILE_C - TT;
    const int blin = (img*4 + cs)*8 + rb;      // 0..255
    unsigned* flags = (unsigned*)(ws + FLAG_OFS);

    // neighbor block id for the 8 poller threads (same image, 8-neighborhood)
    int nb = -1;
    if (tid < 8) {
        int t = (tid < 4) ? tid : tid + 1;
        int dr = t/3 - 1, dc = t%3 - 1;
        int nrb = rb + dr, ncs = cs + dc;
        if (nrb >= 0 && nrb < 8 && ncs >= 0 && ncs < 4)
            nb = (img*4 + ncs)*8 + nrb;
    }

    // ---- sweep geometry: wave bands, lane = pair-col ----
    const int wv   = tid >> 6;                 // 0..3
    const int lane = tid & 63;
    const int cpc  = (lane < NCP) ? lane : NCP-1;   // idle lanes shadow cp39
    const bool wr  = (lane < NCP);
    const int rb0  = wv * BAND;
    const int fb   = 4 + 4*cpc;
    const int idxL = ((lane - 1) & 63) << 2;
    const int idxR = ((lane + 1) & 63) << 2;

    // ---- coefficient plane into LDS (computed ONCE) ----
    {
        const float* __restrict__ xit = x + img*3*PLANE;
        const float* __restrict__ xix = xit + PLANE;
        const float* __restrict__ xiy = xix + PLANE;
        for (int k = tid; k < ER*NCP; k += NTHR) {
            int r = k / NCP, c = k - r*NCP;
            int gr = er0 + r;
            float v10[10];
            #pragma unroll
            for (int j = 0; j < 10; ++j) v10[j] = 0.f;
            #pragma unroll
            for (int j = 0; j < 2; ++j) {
                int gc = ec0 + 2*c + j;
                if (gr >= 0 && gr < HH && gc >= 0 && gc < WW) {
                    int q = gr*WW + gc;
                    float it = xit[q], ix = xix[q], iy = xiy[q];
                    float rd = 1.0f / (1.0f + ix*ix + iy*iy);
                    const float s12 = 1.0f/12.0f;
                    v10[0+j] = (1.0f - ix*ix*rd) * s12;   // ca
                    v10[2+j] = (ix*iy*rd) * s12;          // cb
                    v10[4+j] = ix*it*rd;                  // cc
                    v10[6+j] = (1.0f - iy*iy*rd) * s12;   // cd
                    v10[8+j] = iy*it*rd;                  // ce
                }
            }
            float* cp_ = coef + k*CPP;
            *(float4*)(cp_)     = make_float4(v10[0], v10[1], v10[2], v10[3]);
            *(float4*)(cp_ + 4) = make_float4(v10[4], v10[5], v10[6], v10[7]);
            *(float2*)(cp_ + 8) = make_float2(v10[8], v10[9]);
        }
    }

    // ---- initial full ext-tile stage from est (interleave on the fly) ----
    {
        const float* __restrict__ eu = est + img*2*PLANE;
        const float* __restrict__ ev = eu + PLANE;
        for (int k = tid; k < ER*NCP; k += NTHR) {
            int r = k / NCP, c = k - r*NCP;
            int gr = er0 + r, gc = ec0 + 2*c;
            float2 uu = make_float2(0.f,0.f), vv = make_float2(0.f,0.f);
            if (gr >= 0 && gr < HH && gc >= 0 && gc < WW) {
                uu = *(const float2*)(eu + gr*WW + gc);
                vv = *(const float2*)(ev + gr*WW + gc);
            }
            *(float4*)(s0 + 4 + RS*r + 4*c) = make_float4(uu.x, vv.x, uu.y, vv.y);
        }
    }
    __syncthreads();

    for (int p = 0; p < 13; ++p) {
        const int nInt = (p < 12) ? 4 : 2;     // double-steps (8 or 4 iters)

        for (int q = 0; q < nInt; ++q) {       // one barrier per TWO iterations
            const float* in_ = (q & 1) ? s1 : s0;
            float*       out_= (q & 1) ? s0 : s1;
            hs_interval2(in_, out_, coef, fb, cpc, rb0, idxL, idxR, wr);
            __syncthreads();
        }
        // result now in s0 (nInt even)

        if (p < 12) {
            float* ring = ws + (unsigned)(p & 1) * RING_OFS + img*RIMG;

            // ---- write depth-8 ring of inner tile (coherent 8B stores) ----
            for (int k = tid; k < 640; k += NTHR) {
                int m = k; int r, c2;
                if (m < 256)      { r = m >> 5;              c2 = m & 31; }
                else if (m < 512) { r = 24 + ((m-256) >> 5); c2 = (m-256) & 31; }
                else { int mm = m - 512; r = 8 + (mm >> 3); int t = mm & 7; c2 = (t < 4) ? t : 24 + t; }
                const float* sp = s0 + 4 + RS*(r + TT) + 4*(c2 + 4);
                float* gp = ring + ((rb*TILE_R + r)*(WW/2) + cs*(TILE_C/2) + c2)*4;
                __hip_atomic_store((ull*)gp,     *(const ull*)sp,       __ATOMIC_RELAXED, __HIP_MEMORY_SCOPE_AGENT);
                __hip_atomic_store((ull*)gp + 1, *(const ull*)(sp + 2), __ATOMIC_RELAXED, __HIP_MEMORY_SCOPE_AGENT);
            }
            asm volatile("s_waitcnt vmcnt(0)" ::: "memory");
            __syncthreads();
            if (tid == 0)
                __hip_atomic_store(&flags[p*NBLK + blin], 0x5eed0100u + (unsigned)p,
                                   __ATOMIC_RELAXED, __HIP_MEMORY_SCOPE_AGENT);
            asm volatile("" ::: "memory");
            if (tid < 8 && nb >= 0) {
                const unsigned tgt = 0x5eed0100u + (unsigned)p;
                while (__hip_atomic_load(&flags[p*NBLK + nb],
                                         __ATOMIC_RELAXED, __HIP_MEMORY_SCOPE_AGENT) != tgt)
                    __builtin_amdgcn_s_sleep(1);
            }
            __syncthreads();

            // ---- restage ext halo ring from neighbors (coherent 8B loads) ----
            for (int k = tid; k < 896; k += NTHR) {
                int m = k; int r, c2;
                if (m < 320)      { r = m / 40;              c2 = m - (m/40)*40; }
                else if (m < 640) { int mm = m-320; r = 40 + mm/40; c2 = mm - (mm/40)*40; }
                else { int mm = m - 640; r = 8 + (mm >> 3); int t = mm & 7; c2 = (t < 4) ? t : 32 + t; }
                int gr = er0 + r, gc2 = cs*(TILE_C/2) - 4 + c2;
                ull v0 = 0, v1 = 0;
                if (gr >= 0 && gr < HH && gc2 >= 0 && gc2 < WW/2) {
                    const float* gp = ring + (gr*(WW/2) + gc2)*4;
                    v0 = __hip_atomic_load((const ull*)gp,     __ATOMIC_RELAXED, __HIP_MEMORY_SCOPE_AGENT);
                    v1 = __hip_atomic_load((const ull*)gp + 1, __ATOMIC_RELAXED, __HIP_MEMORY_SCOPE_AGENT);
                }
                float* sp = s0 + 4 + RS*r + 4*c2;
                *(ull*)sp = v0;
                *(ull*)(sp + 2) = v1;
            }
            __syncthreads();
        }
    }

    // ---- final: de-interleave inner tile to planar out ----
    {
        float* ou = out + img*2*PLANE;
        float* ov = ou + PLANE;
        for (int k = tid; k < 1024; k += NTHR) {
            int r = k >> 5, c2 = k & 31;
            float4 V = *(const float4*)(s0 + 4 + RS*(r + TT) + 4*(c2 + 4));
            int q = (rb*TILE_R + r)*WW + cs*TILE_C + 2*c2;
            *(float2*)(ou + q) = make_float2(V.x, V.z);
            *(float2*)(ov + q) = make_float2(V.y, V.w);
        }
    }
}

extern "C" void kernel_launch(void* const* d_in, const int* in_sizes, int n_in,
                              void* d_out, int out_size, void* d_ws, size_t ws_size,
                              hipStream_t stream) {
    const float* x   = (const float*)d_in[0];   // (8,3,256,256) fp32
    const float* est = (const float*)d_in[1];   // (8,2,256,256) fp32
    float* out = (float*)d_out;
    float* ws  = (float*)d_ws;                  // ring slot0 @0, slot1 @8MB, flags @16MB

    // 153.7 KB dynamic LDS (2 field buffers + coeff plane), 1 block/CU.
    hipFuncSetAttribute((const void*)hs_mega,
                        hipFuncAttributeMaxDynamicSharedMemorySize, SMEM_FLOATS*4);

    dim3 grid(8, WW/TILE_C, HH/TILE_R);         // 256 blocks, all co-resident
    dim3 blk(NTHR);
    hs_mega<<<grid, blk, SMEM_FLOATS*4, stream>>>(x, est, out, ws);
}

// Round 13
// 239.427 us; speedup vs baseline: 1.2032x; 1.2032x over previous
//
#include <hip/hip_runtime.h>

typedef unsigned long long ull;

#define HH 256
#define WW 256
#define PLANE (HH*WW)
#define TILE_R 32
#define TILE_C 64
#define TT 8
#define ER 48                // ext rows
#define EC 80                // ext cols -> 40 pairs
#define NCP 40
#define NTHR 256             // 4 waves; wave w owns ext rows [12w, 12w+12)
#define BAND 12
#define RS 160               // floats per LDS row (40 pairs x 4)
#define LBUF (4 + ER*RS + 4) // 7688 floats per buffer
#define CPP 12               // coeff floats per pair (10 used + 2 pad)
#define SMEM_FLOATS (2*LBUF + ER*NCP*CPP)   // 153,664 B

#define RING_OFS (2u*1024u*1024u)
#define FLAG_OFS (4u*1024u*1024u)
#define RIMG (HH*(WW/2)*4)
#define NBLK 256

// TWO Jacobi iterations per call, batched flat (no rolling windows):
// phase 1: read 16 prev rows (own pair) + horizontal sums
// phase 2: 14 A-row updates (iter s)
// phase 3: 56 batched bpermutes -> A horizontal sums
// phase 4: 12 B-row updates (iter s+1) + LDS writes
// One __syncthreads per call (outside). Semantics identical to R12 (verified).
__device__ __forceinline__ void hs_double(
    const float* __restrict__ rbuf, float* __restrict__ wbuf,
    const float* __restrict__ coef,
    int fb, int cpc, int r0, int idxL, int idxR, bool wr,
    const float4* __restrict__ k0r, const float4* __restrict__ k1r,
    const float2* __restrict__ k2r)
{
    // ---- phase 1: batched reads + horizontal sums (rows r0-2 .. r0+13) ----
    float4 h[BAND+4], Mc[BAND+4];
    #pragma unroll
    for (int j = 0; j < BAND+4; ++j) {
        int r = r0 - 2 + j; r = r < 0 ? 0 : (r > ER-1 ? ER-1 : r);   // clamp: ring-0 only
        const float* pr = rbuf + RS*r + fb;
        float2 L = *(const float2*)(pr - 2);
        float4 M = *(const float4*)(pr);
        float2 R = *(const float2*)(pr + 4);
        h[j].x = fmaf(2.f, M.x, L.x) + M.z;  h[j].y = fmaf(2.f, M.z, M.x) + R.x;
        h[j].z = fmaf(2.f, M.y, L.y) + M.w;  h[j].w = fmaf(2.f, M.w, M.y) + R.y;
        Mc[j] = M;
    }

    // ---- phase 2: A updates, rows r0-1 .. r0+12 (14 rows, own 2 cols) ----
    float4 Av[BAND+2];
    #pragma unroll
    for (int j = 0; j < BAND+2; ++j) {
        float4 K0; float4 K1; float2 K2;
        if (j == 0 || j == BAND+1) {       // boundary coeff rows from LDS plane
            int ra = r0 - 1 + j; ra = ra < 0 ? 0 : (ra > ER-1 ? ER-1 : ra);
            const float* cp_ = coef + (ra*NCP + cpc)*CPP;
            K0 = *(const float4*)(cp_);
            K1 = *(const float4*)(cp_ + 4);
            K2 = *(const float2*)(cp_ + 8);
        } else {
            K0 = k0r[j-1]; K1 = k1r[j-1]; K2 = k2r[j-1];
        }
        float tux = fmaf(-4.f, Mc[j+1].x, fmaf(2.f, h[j+1].x, h[j].x) + h[j+2].x);
        float tuy = fmaf(-4.f, Mc[j+1].z, fmaf(2.f, h[j+1].y, h[j].y) + h[j+2].y);
        float tvx = fmaf(-4.f, Mc[j+1].y, fmaf(2.f, h[j+1].z, h[j].z) + h[j+2].z);
        float tvy = fmaf(-4.f, Mc[j+1].w, fmaf(2.f, h[j+1].w, h[j].w) + h[j+2].w);
        Av[j].x = fmaf(K0.x, tux, -fmaf(K0.z, tvx, K1.x));   // u col0
        Av[j].y = fmaf(K1.z, tvx, -fmaf(K0.z, tux, K2.x));   // v col0
        Av[j].z = fmaf(K0.y, tuy, -fmaf(K0.w, tvy, K1.y));   // u col1
        Av[j].w = fmaf(K1.w, tvy, -fmaf(K0.w, tuy, K2.y));   // v col1
    }

    // ---- phase 3: batched cross-lane A-neighbors + A horizontal sums ----
    float4 Ah[BAND+2];
    #pragma unroll
    for (int j = 0; j < BAND+2; ++j) {
        float uL = __int_as_float(__builtin_amdgcn_ds_bpermute(idxL, __float_as_int(Av[j].z)));
        float vL = __int_as_float(__builtin_amdgcn_ds_bpermute(idxL, __float_as_int(Av[j].w)));
        float uR = __int_as_float(__builtin_amdgcn_ds_bpermute(idxR, __float_as_int(Av[j].x)));
        float vR = __int_as_float(__builtin_amdgcn_ds_bpermute(idxR, __float_as_int(Av[j].y)));
        Ah[j].x = fmaf(2.f, Av[j].x, uL) + Av[j].z;  Ah[j].y = fmaf(2.f, Av[j].z, Av[j].x) + uR;
        Ah[j].z = fmaf(2.f, Av[j].y, vL) + Av[j].w;  Ah[j].w = fmaf(2.f, Av[j].w, Av[j].y) + vR;
    }

    // ---- phase 4: B updates, rows r0 .. r0+11, write to out-buffer ----
    #pragma unroll
    for (int j = 0; j < BAND; ++j) {
        float4 K0 = k0r[j]; float4 K1 = k1r[j]; float2 K2 = k2r[j];
        float Tux = fmaf(-4.f, Av[j+1].x, fmaf(2.f, Ah[j+1].x, Ah[j].x) + Ah[j+2].x);
        float Tuy = fmaf(-4.f, Av[j+1].z, fmaf(2.f, Ah[j+1].y, Ah[j].y) + Ah[j+2].y);
        float Tvx = fmaf(-4.f, Av[j+1].y, fmaf(2.f, Ah[j+1].z, Ah[j].z) + Ah[j+2].z);
        float Tvy = fmaf(-4.f, Av[j+1].w, fmaf(2.f, Ah[j+1].w, Ah[j].w) + Ah[j+2].w);
        float4 bv;
        bv.x = fmaf(K0.x, Tux, -fmaf(K0.z, Tvx, K1.x));
        bv.y = fmaf(K1.z, Tvx, -fmaf(K0.z, Tux, K2.x));
        bv.z = fmaf(K0.y, Tuy, -fmaf(K0.w, Tvy, K1.y));
        bv.w = fmaf(K1.w, Tvy, -fmaf(K0.w, Tuy, K2.y));
        if (wr) *(float4*)(wbuf + RS*(r0 + j) + fb) = bv;
    }
}

__global__ __launch_bounds__(NTHR, 1)
void hs_mega(const float* __restrict__ x,     // (8,3,256,256): It, Ix, Iy
             const float* __restrict__ est,   // (8,2,256,256): u0, v0
             float* __restrict__ out,         // (8,2,256,256)
             float* __restrict__ ws)          // rings (double-buffered) + flags
{
    extern __shared__ __align__(16) float smem[];
    float* s0   = smem;
    float* s1   = smem + LBUF;
    float* coef = smem + 2*LBUF;

    const int img = blockIdx.x, cs = blockIdx.y, rb = blockIdx.z;
    const int tid = threadIdx.x;
    const int er0 = rb*TILE_R - TT;
    const int ec0 = cs*TILE_C - TT;
    const int blin = (img*4 + cs)*8 + rb;      // 0..255
    unsigned* flags = (unsigned*)(ws + FLAG_OFS);

    int nb = -1;
    if (tid < 8) {
        int t = (tid < 4) ? tid : tid + 1;
        int dr = t/3 - 1, dc = t%3 - 1;
        int nrb = rb + dr, ncs = cs + dc;
        if (nrb >= 0 && nrb < 8 && ncs >= 0 && ncs < 4)
            nb = (img*4 + ncs)*8 + nrb;
    }

    // ---- sweep geometry: wave bands, lane = pair-col ----
    const int wv   = tid >> 6;                 // 0..3
    const int lane = tid & 63;
    const int cpc  = (lane < NCP) ? lane : NCP-1;   // idle lanes shadow cp39
    const bool wr  = (lane < NCP);
    const int r0   = wv * BAND;
    const int fb   = 4 + 4*cpc;
    const int idxL = ((lane - 1) & 63) << 2;
    const int idxR = ((lane + 1) & 63) << 2;

    // ---- coefficient plane into LDS (computed ONCE) ----
    {
        const float* __restrict__ xit = x + img*3*PLANE;
        const float* __restrict__ xix = xit + PLANE;
        const float* __restrict__ xiy = xix + PLANE;
        for (int k = tid; k < ER*NCP; k += NTHR) {
            int r = k / NCP, c = k - r*NCP;
            int gr = er0 + r;
            float v10[10];
            #pragma unroll
            for (int j = 0; j < 10; ++j) v10[j] = 0.f;
            #pragma unroll
            for (int j = 0; j < 2; ++j) {
                int gc = ec0 + 2*c + j;
                if (gr >= 0 && gr < HH && gc >= 0 && gc < WW) {
                    int q = gr*WW + gc;
                    float it = xit[q], ix = xix[q], iy = xiy[q];
                    float rd = 1.0f / (1.0f + ix*ix + iy*iy);
                    const float s12 = 1.0f/12.0f;
                    v10[0+j] = (1.0f - ix*ix*rd) * s12;   // ca
                    v10[2+j] = (ix*iy*rd) * s12;          // cb
                    v10[4+j] = ix*it*rd;                  // cc
                    v10[6+j] = (1.0f - iy*iy*rd) * s12;   // cd
                    v10[8+j] = iy*it*rd;                  // ce
                }
            }
            float* cp_ = coef + k*CPP;
            *(float4*)(cp_)     = make_float4(v10[0], v10[1], v10[2], v10[3]);
            *(float4*)(cp_ + 4) = make_float4(v10[4], v10[5], v10[6], v10[7]);
            *(float2*)(cp_ + 8) = make_float2(v10[8], v10[9]);
        }
    }

    // ---- initial full ext-tile stage from est (interleave on the fly) ----
    {
        const float* __restrict__ eu = est + img*2*PLANE;
        const float* __restrict__ ev = eu + PLANE;
        for (int k = tid; k < ER*NCP; k += NTHR) {
            int r = k / NCP, c = k - r*NCP;
            int gr = er0 + r, gc = ec0 + 2*c;
            float2 uu = make_float2(0.f,0.f), vv = make_float2(0.f,0.f);
            if (gr >= 0 && gr < HH && gc >= 0 && gc < WW) {
                uu = *(const float2*)(eu + gr*WW + gc);
                vv = *(const float2*)(ev + gr*WW + gc);
            }
            *(float4*)(s0 + 4 + RS*r + 4*c) = make_float4(uu.x, vv.x, uu.y, vv.y);
        }
    }
    __syncthreads();

    // ---- own-band coeffs (rows r0..r0+11) in registers ----
    float4 k0r[BAND], k1r[BAND]; float2 k2r[BAND];
    #pragma unroll
    for (int j = 0; j < BAND; ++j) {
        const float* cp_ = coef + ((r0 + j)*NCP + cpc)*CPP;
        k0r[j] = *(const float4*)(cp_);
        k1r[j] = *(const float4*)(cp_ + 4);
        k2r[j] = *(const float2*)(cp_ + 8);
    }
    __syncthreads();

    for (int p = 0; p < 13; ++p) {
        const int nInt = (p < 12) ? 4 : 2;     // double-steps (8 or 4 iters)

        for (int q = 0; q < nInt; ++q) {       // ONE barrier per TWO iterations
            const float* in_ = (q & 1) ? s1 : s0;
            float*       out_= (q & 1) ? s0 : s1;
            hs_double(in_, out_, coef, fb, cpc, r0, idxL, idxR, wr, k0r, k1r, k2r);
            __syncthreads();
        }
        // result now in s0 (nInt even)

        if (p < 12) {
            float* ring = ws + (unsigned)(p & 1) * RING_OFS + img*RIMG;

            // ---- write depth-8 ring of inner tile (coherent 8B stores) ----
            for (int k = tid; k < 640; k += NTHR) {
                int m = k; int r, c2;
                if (m < 256)      { r = m >> 5;              c2 = m & 31; }
                else if (m < 512) { r = 24 + ((m-256) >> 5); c2 = (m-256) & 31; }
                else { int mm = m - 512; r = 8 + (mm >> 3); int t = mm & 7; c2 = (t < 4) ? t : 24 + t; }
                const float* sp = s0 + 4 + RS*(r + TT) + 4*(c2 + 4);
                float* gp = ring + ((rb*TILE_R + r)*(WW/2) + cs*(TILE_C/2) + c2)*4;
                __hip_atomic_store((ull*)gp,     *(const ull*)sp,       __ATOMIC_RELAXED, __HIP_MEMORY_SCOPE_AGENT);
                __hip_atomic_store((ull*)gp + 1, *(const ull*)(sp + 2), __ATOMIC_RELAXED, __HIP_MEMORY_SCOPE_AGENT);
            }
            asm volatile("s_waitcnt vmcnt(0)" ::: "memory");
            __syncthreads();
            if (tid == 0)
                __hip_atomic_store(&flags[p*NBLK + blin], 0x5eed0100u + (unsigned)p,
                                   __ATOMIC_RELAXED, __HIP_MEMORY_SCOPE_AGENT);
            asm volatile("" ::: "memory");
            if (tid < 8 && nb >= 0) {
                const unsigned tgt = 0x5eed0100u + (unsigned)p;
                while (__hip_atomic_load(&flags[p*NBLK + nb],
                                         __ATOMIC_RELAXED, __HIP_MEMORY_SCOPE_AGENT) != tgt)
                    __builtin_amdgcn_s_sleep(1);
            }
            __syncthreads();

            // ---- restage ext halo ring from neighbors (coherent 8B loads) ----
            for (int k = tid; k < 896; k += NTHR) {
                int m = k; int r, c2;
                if (m < 320)      { r = m / 40;              c2 = m - (m/40)*40; }
                else if (m < 640) { int mm = m-320; r = 40 + mm/40; c2 = mm - (mm/40)*40; }
                else { int mm = m - 640; r = 8 + (mm >> 3); int t = mm & 7; c2 = (t < 4) ? t : 32 + t; }
                int gr = er0 + r, gc2 = cs*(TILE_C/2) - 4 + c2;
                ull v0 = 0, v1 = 0;
                if (gr >= 0 && gr < HH && gc2 >= 0 && gc2 < WW/2) {
                    const float* gp = ring + (gr*(WW/2) + gc2)*4;
                    v0 = __hip_atomic_load((const ull*)gp,     __ATOMIC_RELAXED, __HIP_MEMORY_SCOPE_AGENT);
                    v1 = __hip_atomic_load((const ull*)gp + 1, __ATOMIC_RELAXED, __HIP_MEMORY_SCOPE_AGENT);
                }
                float* sp = s0 + 4 + RS*r + 4*c2;
                *(ull*)sp = v0;
                *(ull*)(sp + 2) = v1;
            }
            __syncthreads();
        }
    }

    // ---- final: de-interleave inner tile to planar out ----
    {
        float* ou = out + img*2*PLANE;
        float* ov = ou + PLANE;
        for (int k = tid; k < 1024; k += NTHR) {
            int r = k >> 5, c2 = k & 31;
            float4 V = *(const float4*)(s0 + 4 + RS*(r + TT) + 4*(c2 + 4));
            int q = (rb*TILE_R + r)*WW + cs*TILE_C + 2*c2;
            *(float2*)(ou + q) = make_float2(V.x, V.z);
            *(float2*)(ov + q) = make_float2(V.y, V.w);
        }
    }
}

extern "C" void kernel_launch(void* const* d_in, const int* in_sizes, int n_in,
                              void* d_out, int out_size, void* d_ws, size_t ws_size,
                              hipStream_t stream) {
    const float* x   = (const float*)d_in[0];   // (8,3,256,256) fp32
    const float* est = (const float*)d_in[1];   // (8,2,256,256) fp32
    float* out = (float*)d_out;
    float* ws  = (float*)d_ws;                  // ring slot0 @0, slot1 @8MB, flags @16MB

    hipFuncSetAttribute((const void*)hs_mega,
                        hipFuncAttributeMaxDynamicSharedMemorySize, SMEM_FLOATS*4);

    dim3 grid(8, WW/TILE_C, HH/TILE_R);         // 256 blocks, all co-resident (1/CU)
    dim3 blk(NTHR);
    hs_mega<<<grid, blk, SMEM_FLOATS*4, stream>>>(x, est, out, ws);
}